// Round 12
// baseline (196.156 us; speedup 1.0000x reference)
//
#include <hip/hip_runtime.h>

#define B 64
#define CL 400
#define QL 50
#define HDIM 1024
#define NEG_INF -1e30f

typedef __bf16 bf16x8v __attribute__((ext_vector_type(8)));
typedef float f32x4 __attribute__((ext_vector_type(4)));

// ---------------- workspace layout (float offsets) ----------------
#define ST_OFF   0
#define S2T_OFF  1280000
#define QB_OFF   2560000
#define S1BF_OFF 2563200
#define QTB_OFF  3480704
#define QHI_OFF  5577856
#define QLO_OFF  7281792
// total 8,985,728 floats = 35.9 MB

__device__ inline ushort f2bf(float x) {
    __bf16 b = (__bf16)x;
    return __builtin_bit_cast(unsigned short, b);
}
__device__ inline void splitbf(float x, ushort& hi, ushort& lo) {
    __bf16 bh = (__bf16)x;
    float hf = (float)bh;
    hi = __builtin_bit_cast(unsigned short, bh);
    __bf16 bl = (__bf16)(x - hf);
    lo = __builtin_bit_cast(unsigned short, bl);
}

// ========== K1: one pass over q -> qhi/qlo, qtb, qb ======================
__global__ __launch_bounds__(256) void k_qprep(
    const float* __restrict__ q, const float* __restrict__ qw,
    const float* __restrict__ cqw, const float* __restrict__ cw,
    const float* __restrict__ bias, ushort* __restrict__ qhi,
    ushort* __restrict__ qlo, ushort* __restrict__ qtb,
    float* __restrict__ qb)
{
    int b = blockIdx.y;
    int blk = blockIdx.x;
    int tid = threadIdx.x;

    if (blk == 16) {
        int wid = tid >> 6, lane = tid & 63;
        for (int j = wid; j < QL; j += 4) {
            const float* qrow = q + ((size_t)b * QL + j) * HDIM;
            float s = 0.f;
            #pragma unroll
            for (int f = 0; f < 4; ++f) {
                float4 a = *(const float4*)(qrow + lane * 4 + f * 256);
                float4 w = *(const float4*)(qw + lane * 4 + f * 256);
                s += a.x * w.x + a.y * w.y + a.z * w.z + a.w * w.w;
            }
            #pragma unroll
            for (int off = 32; off; off >>= 1) s += __shfl_down(s, off);
            if (lane == 0) qb[b * QL + j] = s + bias[0];
        }
        return;
    }

    int h0 = blk * 64;
    __shared__ ushort t[64][72];
    int h4 = tid & 15, jr = tid >> 4;
    float4 wq = *(const float4*)(cqw + h0 + h4 * 4);
    #pragma unroll
    for (int p = 0; p < 4; ++p) {
        int j = jr + p * 16;
        float4 v = make_float4(0.f, 0.f, 0.f, 0.f);
        if (j < QL) v = *(const float4*)(q + ((size_t)b * QL + j) * HDIM + h0 + h4 * 4);
        t[h4 * 4 + 0][j] = f2bf(v.x);
        t[h4 * 4 + 1][j] = f2bf(v.y);
        t[h4 * 4 + 2][j] = f2bf(v.z);
        t[h4 * 4 + 3][j] = f2bf(v.w);
        if (j < 52) {
            float4 src;
            if (j < QL) {
                src.x = v.x * wq.x; src.y = v.y * wq.y;
                src.z = v.z * wq.z; src.w = v.w * wq.w;
            } else if (j == QL) {
                src = *(const float4*)(cw + h0 + h4 * 4);
            } else {
                src = make_float4(0.f, 0.f, 0.f, 0.f);
            }
            ushort4 hh, ll;
            splitbf(src.x, hh.x, ll.x); splitbf(src.y, hh.y, ll.y);
            splitbf(src.z, hh.z, ll.z); splitbf(src.w, hh.w, ll.w);
            *(ushort4*)(qhi + ((size_t)b * 52 + j) * HDIM + h0 + h4 * 4) = hh;
            *(ushort4*)(qlo + ((size_t)b * 52 + j) * HDIM + h0 + h4 * 4) = ll;
        }
    }
    __syncthreads();
    int hr = tid >> 2, seg = tid & 3;
    ushort* dst = qtb + ((size_t)b * HDIM + h0 + hr) * 64 + seg * 16;
    *(uint4*)(dst)     = *(uint4*)(&t[hr][seg * 16]);
    *(uint4*)(dst + 8) = *(uint4*)(&t[hr][seg * 16 + 8]);
}

// ========== K2: S = ch@(qh+ql)^T (2-term MFMA) + fused softmax ===========
// Register-prefetch pipeline (T14): chunk k+1's global loads issue right
// after chunk k's LDS writes, draining under the MFMA phase. Grid is only
// 1.75 blocks/CU so there is no TLP to hide load latency implicitly.
#define ASTR 72
__global__ __launch_bounds__(256) void k_sgemm(
    const float* __restrict__ c, const ushort* __restrict__ qhi,
    const ushort* __restrict__ qlo, const float* __restrict__ qb,
    const int* __restrict__ qmask,
    float* __restrict__ St, ushort* __restrict__ s1bf)
{
    int b  = blockIdx.y;
    int i0 = blockIdx.x * 64;
    int tid = threadIdx.x;
    int wid = tid >> 6, lane = tid & 63;

    __shared__ __align__(16) ushort smem_u[3 * 64 * ASTR];   // 27,648 B
    ushort* Ah = smem_u;
    ushort* Bh = smem_u + 1 * 64 * ASTR;
    ushort* Bl = smem_u + 2 * 64 * ASTR;
    float*  raw = (float*)smem_u;

    const float* cb = c + (size_t)b * CL * HDIM;

    int row = tid >> 2;
    int kq  = (tid & 3) * 16;
    const float*  crow = (i0 + row < CL) ? cb + (size_t)(i0 + row) * HDIM : nullptr;
    const ushort* qhr  = (row < 52) ? qhi + ((size_t)b * 52 + row) * HDIM : nullptr;
    const ushort* qlr  = (row < 52) ? qlo + ((size_t)b * 52 + row) * HDIM : nullptr;

    if (row >= 52) {
        ushort4 z = {0, 0, 0, 0};
        #pragma unroll
        for (int f = 0; f < 4; ++f) {
            *(ushort4*)(&Bh[row * ASTR + kq + f * 4]) = z;
            *(ushort4*)(&Bl[row * ASTR + kq + f * 4]) = z;
        }
    }

    int arow = (wid << 4) + (lane & 15);
    int koff = (lane >> 4) << 3;
    int brow = lane & 15;

    // prefetch registers
    float4 pa[4];
    uint4  pbh[2], pbl[2];

    // LOAD(chunk at k0): global -> regs
    #define SG_LOAD(K0)                                                        \
        do {                                                                   \
            if (crow) {                                                        \
                _Pragma("unroll")                                              \
                for (int f = 0; f < 4; ++f)                                    \
                    pa[f] = *(const float4*)(crow + (K0) + kq + f * 4);        \
            }                                                                  \
            if (qhr) {                                                         \
                pbh[0] = *(const uint4*)(qhr + (K0) + kq);                     \
                pbh[1] = *(const uint4*)(qhr + (K0) + kq + 8);                 \
                pbl[0] = *(const uint4*)(qlr + (K0) + kq);                     \
                pbl[1] = *(const uint4*)(qlr + (K0) + kq + 8);                 \
            }                                                                  \
        } while (0)

    SG_LOAD(0);

    f32x4 acc[4] = {};
    for (int k0 = 0; k0 < HDIM; k0 += 64) {
        __syncthreads();
        // regs -> LDS
        #pragma unroll
        for (int f = 0; f < 4; ++f) {
            float4 cv = crow ? pa[f] : make_float4(0.f, 0.f, 0.f, 0.f);
            ushort4 h4;
            h4.x = f2bf(cv.x); h4.y = f2bf(cv.y); h4.z = f2bf(cv.z); h4.w = f2bf(cv.w);
            *(ushort4*)(&Ah[row * ASTR + kq + f * 4]) = h4;
        }
        if (qhr) {
            *(uint4*)(&Bh[row * ASTR + kq])     = pbh[0];
            *(uint4*)(&Bh[row * ASTR + kq + 8]) = pbh[1];
            *(uint4*)(&Bl[row * ASTR + kq])     = pbl[0];
            *(uint4*)(&Bl[row * ASTR + kq + 8]) = pbl[1];
        }
        // issue next chunk's loads (drain under MFMA below)
        if (k0 + 64 < HDIM) SG_LOAD(k0 + 64);
        __syncthreads();
        #pragma unroll
        for (int ks = 0; ks < 64; ks += 32) {
            bf16x8v ah = *(const bf16x8v*)(&Ah[arow * ASTR + koff + ks]);
            #pragma unroll
            for (int jt = 0; jt < 4; ++jt) {
                int bo = (jt * 16 + brow) * ASTR + koff + ks;
                bf16x8v bh = *(const bf16x8v*)(&Bh[bo]);
                bf16x8v bl = *(const bf16x8v*)(&Bl[bo]);
                acc[jt] = __builtin_amdgcn_mfma_f32_16x16x32_bf16(ah, bl, acc[jt], 0, 0, 0);
                acc[jt] = __builtin_amdgcn_mfma_f32_16x16x32_bf16(ah, bh, acc[jt], 0, 0, 0);
            }
        }
    }
    #undef SG_LOAD
    __syncthreads();
    #pragma unroll
    for (int jt = 0; jt < 4; ++jt)
        #pragma unroll
        for (int rg = 0; rg < 4; ++rg)
            raw[((wid << 4) + ((lane >> 4) << 2) + rg) * 65 + jt * 16 + (lane & 15)] = acc[jt][rg];
    __syncthreads();
    if (tid < 64 && i0 + tid < CL) {
        int i = i0 + tid;
        float* rrow = raw + tid * 65;
        float sc = rrow[50];
        const float* qbb = qb + b * QL;
        const int*   qm  = qmask + b * QL;
        float*  Stp  = St + (size_t)b * QL * CL + i;
        ushort* s1r  = s1bf + ((size_t)b * 448 + i) * 64;
        float m = -3.4e38f;
        for (int j = 0; j < QL; ++j) {
            float s = rrow[j] + sc + qbb[j];
            Stp[(size_t)j * CL] = s;
            float sm = qm[j] ? s : NEG_INF;
            rrow[j] = sm;
            m = fmaxf(m, sm);
        }
        float z = 0.f;
        for (int j = 0; j < QL; ++j) {
            float p = __expf(rrow[j] - m);
            rrow[j] = p; z += p;
        }
        float rz = 1.f / z;
        for (int j = 0; j < QL; ++j) s1r[j] = f2bf(rrow[j] * rz);
        for (int j = QL; j < 64; ++j) s1r[j] = 0;
    }
}

// ========== K3: s2t[b][j][i] = softmax_i(St row, masked) =================
__global__ __launch_bounds__(64) void k_s2(
    const float* __restrict__ St, const int* __restrict__ cmask,
    float* __restrict__ s2t)
{
    int b = blockIdx.y, j = blockIdx.x;
    int t = threadIdx.x;
    const float* row = St + ((size_t)b * QL + j) * CL;
    const int*   cm  = cmask + b * CL;
    float v[7];
    float m = -3.4e38f;
    #pragma unroll
    for (int k = 0; k < 7; ++k) {
        int i = t + k * 64;
        float s = NEG_INF;
        if (i < CL) s = cm[i] ? row[i] : NEG_INF;
        v[k] = s;
        m = fmaxf(m, s);
    }
    #pragma unroll
    for (int off = 32; off; off >>= 1) m = fmaxf(m, __shfl_xor(m, off));
    float z = 0.f;
    #pragma unroll
    for (int k = 0; k < 7; ++k) {
        float p = (t + k * 64 < CL) ? __expf(v[k] - m) : 0.f;
        v[k] = p; z += p;
    }
    #pragma unroll
    for (int off = 32; off; off >>= 1) z += __shfl_xor(z, off);
    float rz = 1.f / z;
    float* dst = s2t + ((size_t)b * QL + j) * CL;
    #pragma unroll
    for (int k = 0; k < 7; ++k) {
        int i = t + k * 64;
        if (i < CL) dst[i] = v[k] * rz;
    }
}

// ========== K4: vtb[b][h][j] = bf16( (s2t @ c)[j][h] ) transposed ========
#define BSTR 40
__global__ __launch_bounds__(256) void k_s2tc(
    const float* __restrict__ s2t, const float* __restrict__ c,
    ushort* __restrict__ vtb)
{
    int b  = blockIdx.y;
    int h0 = blockIdx.x * 64;
    int tid = threadIdx.x;
    int wid = tid >> 6, lane = tid & 63;

    __shared__ __align__(16) ushort As[64 * BSTR];
    __shared__ __align__(16) ushort Bs[64 * BSTR];
    __shared__ __align__(16) ushort tr[64][72];

    const float* ab = s2t + (size_t)b * QL * CL;
    const float* cb = c   + (size_t)b * CL * HDIM;

    int arw = tid >> 2;
    int akq = (tid & 3) * 8;
    int h4  = tid & 15;
    int kcb = tid >> 4;

    int frow = lane & 15;
    int koff = (lane >> 4) << 3;

    f32x4 acc[4] = {};
    for (int k0 = 0; k0 < 416; k0 += 32) {
        __syncthreads();
        #pragma unroll
        for (int f = 0; f < 2; ++f) {
            int kg = k0 + akq + f * 4;
            float4 v = (arw < QL && kg < CL) ? *(const float4*)(ab + (size_t)arw * CL + kg)
                                             : make_float4(0.f,0.f,0.f,0.f);
            ushort4 p;
            p.x = f2bf(v.x); p.y = f2bf(v.y); p.z = f2bf(v.z); p.w = f2bf(v.w);
            *(ushort4*)(&As[arw * BSTR + akq + f * 4]) = p;
        }
        #pragma unroll
        for (int it = 0; it < 2; ++it) {
            int kc = kcb + it * 16;
            int gi = k0 + kc;
            float4 v = (gi < CL) ? *(const float4*)(cb + (size_t)gi * HDIM + h0 + h4 * 4)
                                 : make_float4(0.f,0.f,0.f,0.f);
            Bs[(h4 * 4 + 0) * BSTR + kc] = f2bf(v.x);
            Bs[(h4 * 4 + 1) * BSTR + kc] = f2bf(v.y);
            Bs[(h4 * 4 + 2) * BSTR + kc] = f2bf(v.z);
            Bs[(h4 * 4 + 3) * BSTR + kc] = f2bf(v.w);
        }
        __syncthreads();
        bf16x8v a = *(const bf16x8v*)(&As[((wid << 4) + frow) * BSTR + koff]);
        #pragma unroll
        for (int ht = 0; ht < 4; ++ht) {
            bf16x8v bb = *(const bf16x8v*)(&Bs[(ht * 16 + frow) * BSTR + koff]);
            acc[ht] = __builtin_amdgcn_mfma_f32_16x16x32_bf16(a, bb, acc[ht], 0, 0, 0);
        }
    }
    __syncthreads();
    #pragma unroll
    for (int ht = 0; ht < 4; ++ht)
        #pragma unroll
        for (int rg = 0; rg < 4; ++rg)
            tr[ht * 16 + frow][(wid << 4) + ((lane >> 4) << 2) + rg] = f2bf(acc[ht][rg]);
    __syncthreads();
    int hr = tid >> 2, seg = tid & 3;
    ushort* dst = vtb + ((size_t)b * HDIM + h0 + hr) * 64 + seg * 16;
    *(uint4*)(dst)     = *(uint4*)(&tr[hr][seg * 16]);
    *(uint4*)(dst + 8) = *(uint4*)(&tr[hr][seg * 16 + 8]);
}

// ========== K5: out = [c, a, c*a, c*t] — LDS-reordered coalesced epilogue =
__global__ __launch_bounds__(256) void k_final(
    const float* __restrict__ c, const ushort* __restrict__ s1bf,
    const ushort* __restrict__ qtb, const ushort* __restrict__ vtb,
    float* __restrict__ out)
{
    int b  = blockIdx.z;
    int i0 = blockIdx.x * 64;
    int h0 = blockIdx.y * 64;
    int tid = threadIdx.x;
    int wid = tid >> 6, lane = tid & 63;
    int l15 = lane & 15;
    int hq  = lane >> 4;           // 0..3
    int kof = hq << 3;

    __shared__ __align__(16) ushort qsm[64 * 72];
    __shared__ __align__(16) ushort vsm[64 * 72];
    __shared__ __align__(16) float  alds[64 * 68];

    const float* cb = c + (size_t)b * CL * HDIM;

    int er = tid >> 4;             // 0..15
    int eh = (tid & 15) * 4;       // 0..60

    f32x4 cvr[4] = {};
    #pragma unroll
    for (int rp = 0; rp < 4; ++rp) {
        int gi = i0 + rp * 16 + er;
        if (gi < CL) cvr[rp] = *(const f32x4*)(cb + (size_t)gi * HDIM + h0 + eh);
    }

    const ushort* srow = s1bf + ((size_t)b * 448 + i0 + wid * 16 + l15) * 64;
    bf16x8v sf0 = *(const bf16x8v*)(srow + kof);
    bf16x8v sf1 = *(const bf16x8v*)(srow + 32 + kof);

    {
        int row = tid >> 2, seg = tid & 3;
        const ushort* qsrc = qtb + ((size_t)b * HDIM + h0 + row) * 64 + seg * 16;
        const ushort* vsrc = vtb + ((size_t)b * HDIM + h0 + row) * 64 + seg * 16;
        *(uint4*)(&qsm[row * 72 + seg * 16])     = *(const uint4*)(qsrc);
        *(uint4*)(&qsm[row * 72 + seg * 16 + 8]) = *(const uint4*)(qsrc + 8);
        *(uint4*)(&vsm[row * 72 + seg * 16])     = *(const uint4*)(vsrc);
        *(uint4*)(&vsm[row * 72 + seg * 16 + 8]) = *(const uint4*)(vsrc + 8);
    }
    __syncthreads();

    f32x4 aacc[4], tacc[4];
    #pragma unroll
    for (int ht = 0; ht < 4; ++ht) {
        int ar = (ht * 16 + l15) * 72;
        bf16x8v q0 = *(const bf16x8v*)(&qsm[ar + kof]);
        bf16x8v q1 = *(const bf16x8v*)(&qsm[ar + 32 + kof]);
        bf16x8v v0 = *(const bf16x8v*)(&vsm[ar + kof]);
        bf16x8v v1 = *(const bf16x8v*)(&vsm[ar + 32 + kof]);
        f32x4 z = {};
        aacc[ht] = __builtin_amdgcn_mfma_f32_16x16x32_bf16(q1, sf1,
                     __builtin_amdgcn_mfma_f32_16x16x32_bf16(q0, sf0, z, 0, 0, 0), 0, 0, 0);
        tacc[ht] = __builtin_amdgcn_mfma_f32_16x16x32_bf16(v1, sf1,
                     __builtin_amdgcn_mfma_f32_16x16x32_bf16(v0, sf0, z, 0, 0, 0), 0, 0, 0);
    }

    float* ob = out + (size_t)b * CL * 4 * HDIM;

    // ---- pass A: a -> alds -> coalesced stores of [c, a, c*a] ----
    #pragma unroll
    for (int ht = 0; ht < 4; ++ht)
        *(f32x4*)(&alds[(wid * 16 + l15) * 68 + ht * 16 + hq * 4]) = aacc[ht];
    __syncthreads();
    #pragma unroll
    for (int rp = 0; rp < 4; ++rp) {
        int gi = i0 + rp * 16 + er;
        if (gi < CL) {
            f32x4 av  = *(const f32x4*)(&alds[(rp * 16 + er) * 68 + eh]);
            f32x4 cav = cvr[rp] * av;
            size_t o = (size_t)gi * (4 * HDIM) + h0 + eh;
            __builtin_nontemporal_store(cvr[rp], (f32x4*)(ob + o));
            __builtin_nontemporal_store(av,      (f32x4*)(ob + o + HDIM));
            __builtin_nontemporal_store(cav,     (f32x4*)(ob + o + 2 * HDIM));
        }
    }
    __syncthreads();

    // ---- pass B: t -> alds -> coalesced stores of [c*t] ----
    #pragma unroll
    for (int ht = 0; ht < 4; ++ht)
        *(f32x4*)(&alds[(wid * 16 + l15) * 68 + ht * 16 + hq * 4]) = tacc[ht];
    __syncthreads();
    #pragma unroll
    for (int rp = 0; rp < 4; ++rp) {
        int gi = i0 + rp * 16 + er;
        if (gi < CL) {
            f32x4 tv  = *(const f32x4*)(&alds[(rp * 16 + er) * 68 + eh]);
            f32x4 ctv = cvr[rp] * tv;
            size_t o = (size_t)gi * (4 * HDIM) + h0 + eh;
            __builtin_nontemporal_store(ctv, (f32x4*)(ob + o + 3 * HDIM));
        }
    }
}

extern "C" void kernel_launch(void* const* d_in, const int* in_sizes, int n_in,
                              void* d_out, int out_size, void* d_ws, size_t ws_size,
                              hipStream_t stream) {
    const float* c     = (const float*)d_in[0];
    const float* q     = (const float*)d_in[1];
    const int*   cmask = (const int*)d_in[2];
    const int*   qmask = (const int*)d_in[3];
    const float* cw    = (const float*)d_in[4];
    const float* qw    = (const float*)d_in[5];
    const float* cqw   = (const float*)d_in[6];
    const float* bias  = (const float*)d_in[7];
    float* out = (float*)d_out;
    float* ws  = (float*)d_ws;

    float*  St   = ws + ST_OFF;
    float*  s2t  = ws + S2T_OFF;
    float*  qb   = ws + QB_OFF;
    ushort* s1bf = (ushort*)(ws + S1BF_OFF);
    ushort* qtb  = (ushort*)(ws + QTB_OFF);
    ushort* qhi  = (ushort*)(ws + QHI_OFF);
    ushort* qlo  = (ushort*)(ws + QLO_OFF);
    ushort* vtb  = (ushort*)(ws + QHI_OFF);   // alias: qhi dead after k_sgemm

    k_qprep<<<dim3(17, B), 256, 0, stream>>>(q, qw, cqw, cw, bias, qhi, qlo, qtb, qb);
    k_sgemm<<<dim3(7, B),  256, 0, stream>>>(c, qhi, qlo, qb, qmask, St, s1bf);
    k_s2   <<<dim3(QL, B), 64,  0, stream>>>(St, cmask, s2t);
    k_s2tc <<<dim3(16, B), 256, 0, stream>>>(s2t, c, vtb);
    k_final<<<dim3(7, 16, B), 256, 0, stream>>>(c, s1bf, qtb, vtb, out);
}

// Round 13
// 186.265 us; speedup vs baseline: 1.0531x; 1.0531x over previous
//
#include <hip/hip_runtime.h>

#define B 64
#define CL 400
#define QL 50
#define HDIM 1024
#define NEG_INF -1e30f

typedef __bf16 bf16x8v __attribute__((ext_vector_type(8)));
typedef float f32x4 __attribute__((ext_vector_type(4)));

// ---------------- workspace layout (float offsets) ----------------
#define ST_OFF   0
#define S2T_OFF  1280000
#define QB_OFF   2560000
#define S1BF_OFF 2563200
#define QTB_OFF  3480704
#define QHI_OFF  5577856
#define QLO_OFF  7281792
// total 8,985,728 floats = 35.9 MB

__device__ inline ushort f2bf(float x) {
    __bf16 b = (__bf16)x;
    return __builtin_bit_cast(unsigned short, b);
}
__device__ inline void splitbf(float x, ushort& hi, ushort& lo) {
    __bf16 bh = (__bf16)x;
    float hf = (float)bh;
    hi = __builtin_bit_cast(unsigned short, bh);
    __bf16 bl = (__bf16)(x - hf);
    lo = __builtin_bit_cast(unsigned short, bl);
}

// ========== K1: one pass over q -> qhi/qlo, qtb, qb ======================
__global__ __launch_bounds__(256) void k_qprep(
    const float* __restrict__ q, const float* __restrict__ qw,
    const float* __restrict__ cqw, const float* __restrict__ cw,
    const float* __restrict__ bias, ushort* __restrict__ qhi,
    ushort* __restrict__ qlo, ushort* __restrict__ qtb,
    float* __restrict__ qb)
{
    int b = blockIdx.y;
    int blk = blockIdx.x;
    int tid = threadIdx.x;

    if (blk == 16) {
        int wid = tid >> 6, lane = tid & 63;
        for (int j = wid; j < QL; j += 4) {
            const float* qrow = q + ((size_t)b * QL + j) * HDIM;
            float s = 0.f;
            #pragma unroll
            for (int f = 0; f < 4; ++f) {
                float4 a = *(const float4*)(qrow + lane * 4 + f * 256);
                float4 w = *(const float4*)(qw + lane * 4 + f * 256);
                s += a.x * w.x + a.y * w.y + a.z * w.z + a.w * w.w;
            }
            #pragma unroll
            for (int off = 32; off; off >>= 1) s += __shfl_down(s, off);
            if (lane == 0) qb[b * QL + j] = s + bias[0];
        }
        return;
    }

    int h0 = blk * 64;
    __shared__ ushort t[64][72];
    int h4 = tid & 15, jr = tid >> 4;
    float4 wq = *(const float4*)(cqw + h0 + h4 * 4);
    #pragma unroll
    for (int p = 0; p < 4; ++p) {
        int j = jr + p * 16;
        float4 v = make_float4(0.f, 0.f, 0.f, 0.f);
        if (j < QL) v = *(const float4*)(q + ((size_t)b * QL + j) * HDIM + h0 + h4 * 4);
        t[h4 * 4 + 0][j] = f2bf(v.x);
        t[h4 * 4 + 1][j] = f2bf(v.y);
        t[h4 * 4 + 2][j] = f2bf(v.z);
        t[h4 * 4 + 3][j] = f2bf(v.w);
        if (j < 52) {
            float4 src;
            if (j < QL) {
                src.x = v.x * wq.x; src.y = v.y * wq.y;
                src.z = v.z * wq.z; src.w = v.w * wq.w;
            } else if (j == QL) {
                src = *(const float4*)(cw + h0 + h4 * 4);
            } else {
                src = make_float4(0.f, 0.f, 0.f, 0.f);
            }
            ushort4 hh, ll;
            splitbf(src.x, hh.x, ll.x); splitbf(src.y, hh.y, ll.y);
            splitbf(src.z, hh.z, ll.z); splitbf(src.w, hh.w, ll.w);
            *(ushort4*)(qhi + ((size_t)b * 52 + j) * HDIM + h0 + h4 * 4) = hh;
            *(ushort4*)(qlo + ((size_t)b * 52 + j) * HDIM + h0 + h4 * 4) = ll;
        }
    }
    __syncthreads();
    int hr = tid >> 2, seg = tid & 3;
    ushort* dst = qtb + ((size_t)b * HDIM + h0 + hr) * 64 + seg * 16;
    *(uint4*)(dst)     = *(uint4*)(&t[hr][seg * 16]);
    *(uint4*)(dst + 8) = *(uint4*)(&t[hr][seg * 16 + 8]);
}

// ========== K2: S = ch@(qh+ql)^T (2-term MFMA) + fused softmax (R11) =====
#define ASTR 72
__global__ __launch_bounds__(256) void k_sgemm(
    const float* __restrict__ c, const ushort* __restrict__ qhi,
    const ushort* __restrict__ qlo, const float* __restrict__ qb,
    const int* __restrict__ qmask,
    float* __restrict__ St, ushort* __restrict__ s1bf)
{
    int b  = blockIdx.y;
    int i0 = blockIdx.x * 64;
    int tid = threadIdx.x;
    int wid = tid >> 6, lane = tid & 63;

    __shared__ __align__(16) ushort smem_u[3 * 64 * ASTR];   // 27,648 B
    ushort* Ah = smem_u;
    ushort* Bh = smem_u + 1 * 64 * ASTR;
    ushort* Bl = smem_u + 2 * 64 * ASTR;
    float*  raw = (float*)smem_u;

    const float* cb = c + (size_t)b * CL * HDIM;

    int row = tid >> 2;
    int kq  = (tid & 3) * 16;
    const float*  crow = (i0 + row < CL) ? cb + (size_t)(i0 + row) * HDIM : nullptr;
    const ushort* qhr  = (row < 52) ? qhi + ((size_t)b * 52 + row) * HDIM : nullptr;
    const ushort* qlr  = (row < 52) ? qlo + ((size_t)b * 52 + row) * HDIM : nullptr;

    if (row >= 52) {
        ushort4 z = {0, 0, 0, 0};
        #pragma unroll
        for (int f = 0; f < 4; ++f) {
            *(ushort4*)(&Bh[row * ASTR + kq + f * 4]) = z;
            *(ushort4*)(&Bl[row * ASTR + kq + f * 4]) = z;
        }
    }

    int arow = (wid << 4) + (lane & 15);
    int koff = (lane >> 4) << 3;
    int brow = lane & 15;

    f32x4 acc[4] = {};
    for (int k0 = 0; k0 < HDIM; k0 += 64) {
        __syncthreads();
        #pragma unroll
        for (int f = 0; f < 4; ++f) {
            int k = kq + f * 4;
            float4 cv = crow ? *(const float4*)(crow + k0 + k) : make_float4(0.f,0.f,0.f,0.f);
            ushort4 h4;
            h4.x = f2bf(cv.x); h4.y = f2bf(cv.y); h4.z = f2bf(cv.z); h4.w = f2bf(cv.w);
            *(ushort4*)(&Ah[row * ASTR + k]) = h4;
        }
        if (qhr) {
            *(uint4*)(&Bh[row * ASTR + kq])     = *(const uint4*)(qhr + k0 + kq);
            *(uint4*)(&Bh[row * ASTR + kq + 8]) = *(const uint4*)(qhr + k0 + kq + 8);
            *(uint4*)(&Bl[row * ASTR + kq])     = *(const uint4*)(qlr + k0 + kq);
            *(uint4*)(&Bl[row * ASTR + kq + 8]) = *(const uint4*)(qlr + k0 + kq + 8);
        }
        __syncthreads();
        #pragma unroll
        for (int ks = 0; ks < 64; ks += 32) {
            bf16x8v ah = *(const bf16x8v*)(&Ah[arow * ASTR + koff + ks]);
            #pragma unroll
            for (int jt = 0; jt < 4; ++jt) {
                int bo = (jt * 16 + brow) * ASTR + koff + ks;
                bf16x8v bh = *(const bf16x8v*)(&Bh[bo]);
                bf16x8v bl = *(const bf16x8v*)(&Bl[bo]);
                acc[jt] = __builtin_amdgcn_mfma_f32_16x16x32_bf16(ah, bl, acc[jt], 0, 0, 0);
                acc[jt] = __builtin_amdgcn_mfma_f32_16x16x32_bf16(ah, bh, acc[jt], 0, 0, 0);
            }
        }
    }
    __syncthreads();
    #pragma unroll
    for (int jt = 0; jt < 4; ++jt)
        #pragma unroll
        for (int rg = 0; rg < 4; ++rg)
            raw[((wid << 4) + ((lane >> 4) << 2) + rg) * 65 + jt * 16 + (lane & 15)] = acc[jt][rg];
    __syncthreads();
    if (tid < 64 && i0 + tid < CL) {
        int i = i0 + tid;
        float* rrow = raw + tid * 65;
        float sc = rrow[50];
        const float* qbb = qb + b * QL;
        const int*   qm  = qmask + b * QL;
        float*  Stp  = St + (size_t)b * QL * CL + i;
        ushort* s1r  = s1bf + ((size_t)b * 448 + i) * 64;
        float m = -3.4e38f;
        for (int j = 0; j < QL; ++j) {
            float s = rrow[j] + sc + qbb[j];
            Stp[(size_t)j * CL] = s;
            float sm = qm[j] ? s : NEG_INF;
            rrow[j] = sm;
            m = fmaxf(m, sm);
        }
        float z = 0.f;
        for (int j = 0; j < QL; ++j) {
            float p = __expf(rrow[j] - m);
            rrow[j] = p; z += p;
        }
        float rz = 1.f / z;
        for (int j = 0; j < QL; ++j) s1r[j] = f2bf(rrow[j] * rz);
        for (int j = QL; j < 64; ++j) s1r[j] = 0;
    }
}

// ========== K3: s2t[b][j][i] = softmax_i(St row, masked) =================
__global__ __launch_bounds__(64) void k_s2(
    const float* __restrict__ St, const int* __restrict__ cmask,
    float* __restrict__ s2t)
{
    int b = blockIdx.y, j = blockIdx.x;
    int t = threadIdx.x;
    const float* row = St + ((size_t)b * QL + j) * CL;
    const int*   cm  = cmask + b * CL;
    float v[7];
    float m = -3.4e38f;
    #pragma unroll
    for (int k = 0; k < 7; ++k) {
        int i = t + k * 64;
        float s = NEG_INF;
        if (i < CL) s = cm[i] ? row[i] : NEG_INF;
        v[k] = s;
        m = fmaxf(m, s);
    }
    #pragma unroll
    for (int off = 32; off; off >>= 1) m = fmaxf(m, __shfl_xor(m, off));
    float z = 0.f;
    #pragma unroll
    for (int k = 0; k < 7; ++k) {
        float p = (t + k * 64 < CL) ? __expf(v[k] - m) : 0.f;
        v[k] = p; z += p;
    }
    #pragma unroll
    for (int off = 32; off; off >>= 1) z += __shfl_xor(z, off);
    float rz = 1.f / z;
    float* dst = s2t + ((size_t)b * QL + j) * CL;
    #pragma unroll
    for (int k = 0; k < 7; ++k) {
        int i = t + k * 64;
        if (i < CL) dst[i] = v[k] * rz;
    }
}

// ========== K4: vtb[b][h][j] = bf16( (s2t @ c)[j][h] ) transposed ========
#define BSTR 40
__global__ __launch_bounds__(256) void k_s2tc(
    const float* __restrict__ s2t, const float* __restrict__ c,
    ushort* __restrict__ vtb)
{
    int b  = blockIdx.y;
    int h0 = blockIdx.x * 64;
    int tid = threadIdx.x;
    int wid = tid >> 6, lane = tid & 63;

    __shared__ __align__(16) ushort As[64 * BSTR];
    __shared__ __align__(16) ushort Bs[64 * BSTR];
    __shared__ __align__(16) ushort tr[64][72];

    const float* ab = s2t + (size_t)b * QL * CL;
    const float* cb = c   + (size_t)b * CL * HDIM;

    int arw = tid >> 2;
    int akq = (tid & 3) * 8;
    int h4  = tid & 15;
    int kcb = tid >> 4;

    int frow = lane & 15;
    int koff = (lane >> 4) << 3;

    f32x4 acc[4] = {};
    for (int k0 = 0; k0 < 416; k0 += 32) {
        __syncthreads();
        #pragma unroll
        for (int f = 0; f < 2; ++f) {
            int kg = k0 + akq + f * 4;
            float4 v = (arw < QL && kg < CL) ? *(const float4*)(ab + (size_t)arw * CL + kg)
                                             : make_float4(0.f,0.f,0.f,0.f);
            ushort4 p;
            p.x = f2bf(v.x); p.y = f2bf(v.y); p.z = f2bf(v.z); p.w = f2bf(v.w);
            *(ushort4*)(&As[arw * BSTR + akq + f * 4]) = p;
        }
        #pragma unroll
        for (int it = 0; it < 2; ++it) {
            int kc = kcb + it * 16;
            int gi = k0 + kc;
            float4 v = (gi < CL) ? *(const float4*)(cb + (size_t)gi * HDIM + h0 + h4 * 4)
                                 : make_float4(0.f,0.f,0.f,0.f);
            Bs[(h4 * 4 + 0) * BSTR + kc] = f2bf(v.x);
            Bs[(h4 * 4 + 1) * BSTR + kc] = f2bf(v.y);
            Bs[(h4 * 4 + 2) * BSTR + kc] = f2bf(v.z);
            Bs[(h4 * 4 + 3) * BSTR + kc] = f2bf(v.w);
        }
        __syncthreads();
        bf16x8v a = *(const bf16x8v*)(&As[((wid << 4) + frow) * BSTR + koff]);
        #pragma unroll
        for (int ht = 0; ht < 4; ++ht) {
            bf16x8v bb = *(const bf16x8v*)(&Bs[(ht * 16 + frow) * BSTR + koff]);
            acc[ht] = __builtin_amdgcn_mfma_f32_16x16x32_bf16(a, bb, acc[ht], 0, 0, 0);
        }
    }
    __syncthreads();
    #pragma unroll
    for (int ht = 0; ht < 4; ++ht)
        #pragma unroll
        for (int rg = 0; rg < 4; ++rg)
            tr[ht * 16 + frow][(wid << 4) + ((lane >> 4) << 2) + rg] = f2bf(acc[ht][rg]);
    __syncthreads();
    int hr = tid >> 2, seg = tid & 3;
    ushort* dst = vtb + ((size_t)b * HDIM + h0 + hr) * 64 + seg * 16;
    *(uint4*)(dst)     = *(uint4*)(&tr[hr][seg * 16]);
    *(uint4*)(dst + 8) = *(uint4*)(&tr[hr][seg * 16 + 8]);
}

// ========== K5: out = [c, a, c*a, c*t] — unified single-phase epilogue ====
// Both accumulators staged through LDS at once (aldsT overlays the dead
// qsm/vsm region) -> one barrier fewer, all 4 nt-store streams interleaved.
__global__ __launch_bounds__(256) void k_final(
    const float* __restrict__ c, const ushort* __restrict__ s1bf,
    const ushort* __restrict__ qtb, const ushort* __restrict__ vtb,
    float* __restrict__ out)
{
    int b  = blockIdx.z;
    int i0 = blockIdx.x * 64;
    int h0 = blockIdx.y * 64;
    int tid = threadIdx.x;
    int wid = tid >> 6, lane = tid & 63;
    int l15 = lane & 15;
    int hq  = lane >> 4;           // 0..3
    int kof = hq << 3;

    // 35,840 B: [qsm 9216 | vsm 9216 | aldsA 17408]; aldsT overlays qsm+vsm.
    __shared__ __align__(16) char smem[35840];
    ushort* qsm   = (ushort*)smem;             // [64*72]
    ushort* vsm   = (ushort*)(smem + 9216);    // [64*72]
    float*  aldsA = (float*)(smem + 18432);    // [64*68]
    float*  aldsT = (float*)smem;              // [64*68], after MFMA reads done

    const float* cb = c + (size_t)b * CL * HDIM;

    int er = tid >> 4;             // 0..15
    int eh = (tid & 15) * 4;       // 0..60

    f32x4 cvr[4] = {};
    #pragma unroll
    for (int rp = 0; rp < 4; ++rp) {
        int gi = i0 + rp * 16 + er;
        if (gi < CL) cvr[rp] = *(const f32x4*)(cb + (size_t)gi * HDIM + h0 + eh);
    }

    const ushort* srow = s1bf + ((size_t)b * 448 + i0 + wid * 16 + l15) * 64;
    bf16x8v sf0 = *(const bf16x8v*)(srow + kof);
    bf16x8v sf1 = *(const bf16x8v*)(srow + 32 + kof);

    {
        int row = tid >> 2, seg = tid & 3;
        const ushort* qsrc = qtb + ((size_t)b * HDIM + h0 + row) * 64 + seg * 16;
        const ushort* vsrc = vtb + ((size_t)b * HDIM + h0 + row) * 64 + seg * 16;
        *(uint4*)(&qsm[row * 72 + seg * 16])     = *(const uint4*)(qsrc);
        *(uint4*)(&qsm[row * 72 + seg * 16 + 8]) = *(const uint4*)(qsrc + 8);
        *(uint4*)(&vsm[row * 72 + seg * 16])     = *(const uint4*)(vsrc);
        *(uint4*)(&vsm[row * 72 + seg * 16 + 8]) = *(const uint4*)(vsrc + 8);
    }
    __syncthreads();

    f32x4 aacc[4], tacc[4];
    #pragma unroll
    for (int ht = 0; ht < 4; ++ht) {
        int ar = (ht * 16 + l15) * 72;
        bf16x8v q0 = *(const bf16x8v*)(&qsm[ar + kof]);
        bf16x8v q1 = *(const bf16x8v*)(&qsm[ar + 32 + kof]);
        bf16x8v v0 = *(const bf16x8v*)(&vsm[ar + kof]);
        bf16x8v v1 = *(const bf16x8v*)(&vsm[ar + 32 + kof]);
        f32x4 z = {};
        aacc[ht] = __builtin_amdgcn_mfma_f32_16x16x32_bf16(q1, sf1,
                     __builtin_amdgcn_mfma_f32_16x16x32_bf16(q0, sf0, z, 0, 0, 0), 0, 0, 0);
        tacc[ht] = __builtin_amdgcn_mfma_f32_16x16x32_bf16(v1, sf1,
                     __builtin_amdgcn_mfma_f32_16x16x32_bf16(v0, sf0, z, 0, 0, 0), 0, 0, 0);
    }
    __syncthreads();   // all qsm/vsm reads done before aldsT overwrites them

    #pragma unroll
    for (int ht = 0; ht < 4; ++ht) {
        int off = (wid * 16 + l15) * 68 + ht * 16 + hq * 4;
        *(f32x4*)(&aldsA[off]) = aacc[ht];
        *(f32x4*)(&aldsT[off]) = tacc[ht];
    }
    __syncthreads();

    float* ob = out + (size_t)b * CL * 4 * HDIM;
    #pragma unroll
    for (int rp = 0; rp < 4; ++rp) {
        int gi = i0 + rp * 16 + er;
        if (gi < CL) {
            int off = (rp * 16 + er) * 68 + eh;
            f32x4 av  = *(const f32x4*)(&aldsA[off]);
            f32x4 tv  = *(const f32x4*)(&aldsT[off]);
            f32x4 cav = cvr[rp] * av;
            f32x4 ctv = cvr[rp] * tv;
            size_t o = (size_t)gi * (4 * HDIM) + h0 + eh;
            __builtin_nontemporal_store(cvr[rp], (f32x4*)(ob + o));
            __builtin_nontemporal_store(av,      (f32x4*)(ob + o + HDIM));
            __builtin_nontemporal_store(cav,     (f32x4*)(ob + o + 2 * HDIM));
            __builtin_nontemporal_store(ctv,     (f32x4*)(ob + o + 3 * HDIM));
        }
    }
}

extern "C" void kernel_launch(void* const* d_in, const int* in_sizes, int n_in,
                              void* d_out, int out_size, void* d_ws, size_t ws_size,
                              hipStream_t stream) {
    const float* c     = (const float*)d_in[0];
    const float* q     = (const float*)d_in[1];
    const int*   cmask = (const int*)d_in[2];
    const int*   qmask = (const int*)d_in[3];
    const float* cw    = (const float*)d_in[4];
    const float* qw    = (const float*)d_in[5];
    const float* cqw   = (const float*)d_in[6];
    const float* bias  = (const float*)d_in[7];
    float* out = (float*)d_out;
    float* ws  = (float*)d_ws;

    float*  St   = ws + ST_OFF;
    float*  s2t  = ws + S2T_OFF;
    float*  qb   = ws + QB_OFF;
    ushort* s1bf = (ushort*)(ws + S1BF_OFF);
    ushort* qtb  = (ushort*)(ws + QTB_OFF);
    ushort* qhi  = (ushort*)(ws + QHI_OFF);
    ushort* qlo  = (ushort*)(ws + QLO_OFF);
    ushort* vtb  = (ushort*)(ws + QHI_OFF);   // alias: qhi dead after k_sgemm

    k_qprep<<<dim3(17, B), 256, 0, stream>>>(q, qw, cqw, cw, bias, qhi, qlo, qtb, qb);
    k_sgemm<<<dim3(7, B),  256, 0, stream>>>(c, qhi, qlo, qb, qmask, St, s1bf);
    k_s2   <<<dim3(QL, B), 64,  0, stream>>>(St, cmask, s2t);
    k_s2tc <<<dim3(16, B), 256, 0, stream>>>(s2t, c, vtb);
    k_final<<<dim3(7, 16, B), 256, 0, stream>>>(c, s1bf, qtb, vtb, out);
}